// Round 3
// baseline (1147.905 us; speedup 1.0000x reference)
//
#include <hip/hip_runtime.h>
#include <cstddef>
#include <cstdint>

#define B_ 64
#define T_ 800
#define D_ 80
#define H_ 128
#define K_ 39
#define BT_ (B_ * T_)   // 51200

typedef _Float16 h2_t  __attribute__((ext_vector_type(2)));
typedef _Float16 h4_t  __attribute__((ext_vector_type(4)));
typedef _Float16 f16x8 __attribute__((ext_vector_type(8)));
typedef float    f32x4 __attribute__((ext_vector_type(4)));

__device__ __forceinline__ float fdot2_(h2_t a, h2_t b, float c) {
#if __has_builtin(__builtin_amdgcn_fdot2)
  return __builtin_amdgcn_fdot2(a, b, c, false);
#else
  return c + (float)a.x * (float)b.x + (float)a.y * (float)b.y;
#endif
}

__device__ __forceinline__ h2_t asH2u_(uint32_t u) { return __builtin_bit_cast(h2_t, u); }

__device__ __forceinline__ float sigf_(float x)  { return 1.0f / (1.0f + __expf(-x)); }
__device__ __forceinline__ float tanhf_(float x) { return 2.0f / (1.0f + __expf(-2.0f * x)) - 1.0f; }

__device__ __forceinline__ float rcpf_(float x) {
#if __has_builtin(__builtin_amdgcn_rcpf)
  return __builtin_amdgcn_rcpf(x);
#else
  return 1.0f / x;
#endif
}

__device__ __forceinline__ float laneb_(float v, int lane) {
  return __builtin_bit_cast(float, __builtin_amdgcn_readlane(__builtin_bit_cast(int, v), lane));
}
__device__ __forceinline__ uint32_t lanebu_(uint32_t v, int lane) {
  return (uint32_t)__builtin_amdgcn_readlane((int)v, lane);
}

// VALU lane-pair swap via DPP quad_perm[1,0,3,2] (0xB1): lane 2k <-> 2k+1.
__device__ __forceinline__ float dppswap1_(float v) {
  return __builtin_bit_cast(float,
    __builtin_amdgcn_mov_dpp(__builtin_bit_cast(int, v), 0xB1, 0xF, 0xF, true));
}

// LDS-only barrier: waits LDS ops but does NOT drain vmem.
__device__ __forceinline__ void barrier_lds_() {
  asm volatile("s_waitcnt lgkmcnt(0)" ::: "memory");
  __builtin_amdgcn_s_barrier();
}

// fallback lstm lane->gate-rows mapping: wave w, lane L: unit = w*32 + (L>>1),
// role = L&1. role0 owns (i,g) rows, role1 owns (f,o). DPP(1) pairs them.
__device__ __forceinline__ void rows_of_(int tid, int& unit, int& role, int& r0, int& r1) {
  const int w = tid >> 6, L = tid & 63;
  unit = w * 32 + (L >> 1);
  role = L & 1;
  r0 = role * H_ + unit;            // i (role0) or f (role1)
  r1 = 2 * H_ + role * H_ + unit;   // g (role0) or o (role1)
}

// ---------------------------------------------------------------------------
// xw via MFMA 16x16x32 f16. R12: NEW output layout for the MFMA-batched lstm:
//   xw[t][dir][tile32][q4][b64][reg4] f16  (tile = gate-row>>4, q4 = (gr>>2)&3,
//   reg = gr&3), so the lstm lane (batch=lane&15, quad=lane>>4) loads its 4
//   C-rows per tile as ONE b64.
// ---------------------------------------------------------------------------
__global__ __launch_bounds__(256, 1)
void xw_kernel(const float* __restrict__ x,
               const float* __restrict__ Wih_f, const float* __restrict__ Wih_b,
               _Float16* __restrict__ xw)
{
  const int dir = blockIdx.x & 1;
  const int mc  = blockIdx.x >> 1;           // 0..99
  const float* W = dir ? Wih_b : Wih_f;

  const int tid  = threadIdx.x;
  const int w    = tid >> 6;
  const int lane = tid & 63;
  const int lm   = lane & 15;
  const int quad = lane >> 4;

  f16x8 Bf[8][3];
  #pragma unroll
  for (int nt = 0; nt < 8; ++nt) {
    const int r = w * 128 + nt * 16 + lm;    // gate-row this B-frag produces
    #pragma unroll
    for (int kt = 0; kt < 3; ++kt) {
      const int kb = kt * 32 + quad * 8;
      #pragma unroll
      for (int j = 0; j < 8; ++j) {
        const int k = kb + j;
        Bf[nt][kt][j] = (k < D_) ? (_Float16)W[(size_t)r * D_ + k] : (_Float16)0.0f;
      }
    }
  }

  __shared__ alignas(16) _Float16 xs[128 * 96];   // 24 KB, K padded to 96
  for (int i = tid; i < 128 * 96; i += 256) xs[i] = (_Float16)0.0f;

  for (int cc = 0; cc < 4; ++cc) {
    const int base = mc * 512 + cc * 128;
    __syncthreads();
    {
      const float4* src = (const float4*)(x + (size_t)base * D_);
      for (int i = tid; i < 128 * D_ / 4; i += 256) {
        float4 v = src[i];
        const int row = i / 20, col = (i % 20) * 4;
        h2_t p0, p1;
        p0.x = (_Float16)v.x; p0.y = (_Float16)v.y;
        p1.x = (_Float16)v.z; p1.y = (_Float16)v.w;
        uint2 pk;
        pk.x = __builtin_bit_cast(uint32_t, p0);
        pk.y = __builtin_bit_cast(uint32_t, p1);
        *(uint2*)&xs[row * 96 + col] = pk;
      }
    }
    __syncthreads();

    #pragma unroll
    for (int mt = 0; mt < 8; ++mt) {
      f16x8 Af[3];
      #pragma unroll
      for (int kt = 0; kt < 3; ++kt)
        Af[kt] = *(const f16x8*)&xs[(mt * 16 + lm) * 96 + kt * 32 + quad * 8];

      f32x4 acc[8];
      #pragma unroll
      for (int nt = 0; nt < 8; ++nt) acc[nt] = (f32x4){0.f, 0.f, 0.f, 0.f};
      #pragma unroll
      for (int kt = 0; kt < 3; ++kt)
        #pragma unroll
        for (int nt = 0; nt < 8; ++nt)
          acc[nt] = __builtin_amdgcn_mfma_f32_16x16x32_f16(Af[kt], Bf[nt][kt], acc[nt], 0, 0, 0);

      // time/batch decomposition for the 4 C-rows this thread holds
      int tA[4], bA[4];
      #pragma unroll
      for (int rg = 0; rg < 4; ++rg) {
        const int bt = base + mt * 16 + quad * 4 + rg;
        bA[rg] = bt / T_;
        tA[rg] = bt % T_;
      }
      #pragma unroll
      for (int nt = 0; nt < 8; ++nt) {
        // gate-row gr = w*128 + nt*16 + lm -> tile=w*8+nt, q4=lm>>2, reg=lm&3
        #pragma unroll
        for (int rg = 0; rg < 4; ++rg) {
          const size_t addr = (size_t)(tA[rg] * 2 + dir) * 32768
                            + (size_t)(w * 8 + nt) * 1024
                            + (size_t)(lm >> 2) * 256
                            + (size_t)bA[rg] * 4 + (lm & 3);
          xw[addr] = (_Float16)acc[nt][rg];
        }
      }
    }
  }
}

// ---------------------------------------------------------------------------
// R12: MFMA-batched recurrent LSTM. 8 blocks (2 dirs x 4 batch-groups of 16),
// 512 threads (8 waves). Per step per block:
//   Y(512x16) = Whh(512x128, f16 frags in regs) x H_T(16x128 f16, LDS)
// Wave w owns M-tiles {w, w+8, w+16, w+24} -> each lane holds i,f,g,o of the
// SAME 4 units (u = 16w + quad*4 + reg) for batch lm -> cell update is fully
// lane-local. Activations use fused-rcp forms (8 trans/unit) with exact +-12
// clamps before the tanh exps.
// ---------------------------------------------------------------------------
__global__ __launch_bounds__(512, 1)
void lstm_mfma_kernel(const _Float16* __restrict__ xwN,
                      const float* __restrict__ Whh_f, const float* __restrict__ Whh_b,
                      const float* __restrict__ bih_f, const float* __restrict__ bhh_f,
                      const float* __restrict__ bih_b, const float* __restrict__ bhh_b,
                      _Float16* __restrict__ hcat)
{
  const int d  = blockIdx.x & 1;
  const int bg = blockIdx.x >> 1;            // 0..3
  const float* Whh = d ? Whh_b : Whh_f;
  const float* bih = d ? bih_b : bih_f;
  const float* bhh = d ? bhh_b : bhh_f;

  const int tid  = threadIdx.x;
  const int w    = tid >> 6;                 // 0..7
  const int lane = tid & 63;
  const int lm   = lane & 15;                // batch-in-group / frag row
  const int quad = lane >> 4;
  const int bglob = bg * 16 + lm;            // global batch element
  const int u0   = w * 16 + quad * 4;        // first unit this lane owns

  // Whh A-fragments, static in registers (64 VGPRs).
  f16x8 Af[4][4];
  #pragma unroll
  for (int ti = 0; ti < 4; ++ti) {
    const int gr = (w + 8 * ti) * 16 + lm;
    #pragma unroll
    for (int ks = 0; ks < 4; ++ks) {
      const float* src = Whh + (size_t)gr * H_ + ks * 32 + quad * 8;
      #pragma unroll
      for (int j = 0; j < 8; ++j) Af[ti][ks][j] = (_Float16)src[j];
    }
  }
  // biases for the C rows this lane holds
  float bias[4][4];
  #pragma unroll
  for (int ti = 0; ti < 4; ++ti) {
    #pragma unroll
    for (int r = 0; r < 4; ++r) {
      const int gr = (w + 8 * ti) * 16 + quad * 4 + r;
      bias[ti][r] = bih[gr] + bhh[gr];
    }
  }

  __shared__ alignas(16) _Float16 hT[2][16][136];   // [buf][batch][unit], padded
  for (int i = tid; i < 2 * 16 * 136; i += 512) (&hT[0][0][0])[i] = (_Float16)0.0f;
  float c[4] = {0.f, 0.f, 0.f, 0.f};

  auto ldxq = [&](int t, h4_t* xq) {
    const _Float16* p = xwN + (size_t)(t * 2 + d) * 32768
                      + (size_t)quad * 256 + (size_t)bglob * 4;
    #pragma unroll
    for (int ti = 0; ti < 4; ++ti)
      xq[ti] = *(const h4_t*)(p + (size_t)(w + 8 * ti) * 1024);
  };

  h4_t xqA[4], xqB[4];
  ldxq(d ? (T_ - 1) : 0, xqA);
  ldxq(d ? (T_ - 2) : 1, xqB);
  __syncthreads();

  auto step = [&](int tt, int par, h4_t* xq) {
    const int t = d ? (T_ - 1 - tt) : tt;

    f32x4 acc[4];
    #pragma unroll
    for (int ti = 0; ti < 4; ++ti)
      #pragma unroll
      for (int r = 0; r < 4; ++r)
        acc[ti][r] = bias[ti][r] + (float)xq[ti][r];

    {  // prefetch xw for tt+2 (consumed 2 steps later)
      const int ttc = (tt + 2 < T_) ? (tt + 2) : (T_ - 1);
      const int tq  = d ? (T_ - 1 - ttc) : ttc;
      ldxq(tq, xq);
    }

    f16x8 Bf[4];
    #pragma unroll
    for (int ks = 0; ks < 4; ++ks)
      Bf[ks] = *(const f16x8*)&hT[par][lm][ks * 32 + quad * 8];

    #pragma unroll
    for (int ks = 0; ks < 4; ++ks)
      #pragma unroll
      for (int ti = 0; ti < 4; ++ti)
        acc[ti] = __builtin_amdgcn_mfma_f32_16x16x32_f16(Af[ti][ks], Bf[ks], acc[ti], 0, 0, 0);

    h4_t hh;
    #pragma unroll
    for (int r = 0; r < 4; ++r) {
      const float gi = acc[0][r], gf = acc[1][r], gg = acc[2][r], go = acc[3][r];
      const float ei  = __expf(-gi);
      const float gcl = fminf(fmaxf(gg, -12.f), 12.f);
      const float eg  = __expf(-2.f * gcl);
      const float ef  = __expf(-gf);
      const float eo  = __expf(-go);
      const float sitg = (1.f - eg) * rcpf_((1.f + ei) * (1.f + eg)); // sig(i)*tanh(g)
      const float sf   = rcpf_(1.f + ef);                             // sig(f)
      const float cn   = fmaf(sf, c[r], sitg);
      c[r] = cn;
      const float ccl = fminf(fmaxf(cn, -12.f), 12.f);
      const float ec  = __expf(-2.f * ccl);
      const float h   = (1.f - ec) * rcpf_((1.f + eo) * (1.f + ec));  // sig(o)*tanh(c)
      hh[r] = (_Float16)h;
    }

    *(h4_t*)&hT[par ^ 1][lm][u0] = hh;                                // next-step H
    *(h4_t*)(hcat + ((size_t)bglob * T_ + t) * 256 + d * 128 + u0) = hh;  // async
    barrier_lds_();
  };

  for (int tb = 0; tb < T_; tb += 2) {
    step(tb,     0, xqA);
    step(tb + 1, 1, xqB);
  }
}

// ---------------------------------------------------------------------------
// Fallback recurrent LSTM (R1-verified 256-thread version, x@Wih in-kernel).
// Used only when the workspace is too small for xwN.
// ---------------------------------------------------------------------------
__global__ __launch_bounds__(256, 1)
void lstm_fallback_kernel(const float* __restrict__ x,
                 const float* __restrict__ Wih_f, const float* __restrict__ Whh_f,
                 const float* __restrict__ bih_f, const float* __restrict__ bhh_f,
                 const float* __restrict__ Wih_b, const float* __restrict__ Whh_b,
                 const float* __restrict__ bih_b, const float* __restrict__ bhh_b,
                 _Float16* __restrict__ hcat)
{
  const int bb  = blockIdx.x & 63;
  const int dir = blockIdx.x >> 6;
  const float* Whh = dir ? Whh_b : Whh_f;
  const float* Wih = dir ? Wih_b : Wih_f;
  const float* bih = dir ? bih_b : bih_f;
  const float* bhh = dir ? bhh_b : bhh_f;

  const int tid  = threadIdx.x;
  const int lane = tid & 63;
  int unit, role, r0, r1; rows_of_(tid, unit, role, r0, r1);
  const float qc1 = role ? 1.0f : 2.0f;
  const float qc0 = role ? 0.0f : -1.0f;

  h2_t w0[64], w1[64];
  #pragma unroll
  for (int j = 0; j < 64; ++j) {
    float2 a = *(const float2*)(Whh + (size_t)r0 * H_ + 2 * j);
    float2 d = *(const float2*)(Whh + (size_t)r1 * H_ + 2 * j);
    w0[j].x = (_Float16)a.x; w0[j].y = (_Float16)a.y;
    w1[j].x = (_Float16)d.x; w1[j].y = (_Float16)d.y;
  }
  h2_t wx0[40], wx1[40];
  #pragma unroll
  for (int i = 0; i < 40; ++i) {
    float2 a = *(const float2*)(Wih + (size_t)r0 * D_ + 2 * i);
    float2 d = *(const float2*)(Wih + (size_t)r1 * D_ + 2 * i);
    wx0[i].x = (_Float16)a.x; wx0[i].y = (_Float16)a.y;
    wx1[i].x = (_Float16)d.x; wx1[i].y = (_Float16)d.y;
  }
  const float bias0 = bih[r0] + bhh[r0];
  const float bias1 = bih[r1] + bhh[r1];

  __shared__ alignas(8) _Float16 hsf[2][H_];
  __shared__ uint32_t xs2[2][64];

  if (tid < H_) hsf[0][tid] = (_Float16)0.0f;
  if (tid < 64) { xs2[0][tid] = 0u; xs2[1][tid] = 0u; }
  float c = 0.0f;

  const float* xb = x + (size_t)bb * T_ * D_;
  _Float16*    hb = hcat + (size_t)bb * T_ * (2 * H_) + dir * H_;

  h2_t xpend; xpend.x = (_Float16)0.f; xpend.y = (_Float16)0.f;
  {
    const int tq0 = dir ? (T_ - 1) : 0;
    const int tq1 = dir ? (T_ - 2) : 1;
    if (tid < 40) {
      float2 v0 = *(const float2*)(xb + (size_t)tq0 * D_ + 2 * tid);
      h2_t p; p.x = (_Float16)v0.x; p.y = (_Float16)v0.y;
      xs2[0][tid] = __builtin_bit_cast(uint32_t, p);
      float2 v1 = *(const float2*)(xb + (size_t)tq1 * D_ + 2 * tid);
      xpend.x = (_Float16)v1.x; xpend.y = (_Float16)v1.y;
    }
  }
  __syncthreads();

  auto step = [&](int tt, int par) {
    const int t = dir ? (T_ - 1 - tt) : tt;
    float a0 = bias0, a1 = 0.f, b0 = bias1, b1 = 0.f;
    if (tid < 40) {
      xs2[par ^ 1][tid] = __builtin_bit_cast(uint32_t, xpend);
      const int ttc = (tt + 2 < T_) ? (tt + 2) : (T_ - 1);
      const int tq2 = dir ? (T_ - 1 - ttc) : ttc;
      float2 v = *(const float2*)(xb + (size_t)tq2 * D_ + 2 * tid);
      xpend.x = (_Float16)v.x; xpend.y = (_Float16)v.y;
    }
    uint32_t xreg = xs2[par][lane];
    #pragma unroll
    for (int j = 0; j < 40; j += 2) {
      h2_t q0 = asH2u_(lanebu_(xreg, j));
      h2_t q1 = asH2u_(lanebu_(xreg, j + 1));
      a0 = fdot2_(wx0[j],     q0, a0); b0 = fdot2_(wx1[j],     q0, b0);
      a1 = fdot2_(wx0[j + 1], q1, a1); b1 = fdot2_(wx1[j + 1], q1, b1);
    }
    const uint32_t* hq = (const uint32_t*)hsf[par];
    #pragma unroll
    for (int g = 0; g < 64; g += 2) {
      h2_t hv0 = asH2u_(hq[g]);
      h2_t hv1 = asH2u_(hq[g + 1]);
      a0 = fdot2_(w0[g],     hv0, a0); b0 = fdot2_(w1[g],     hv0, b0);
      a1 = fdot2_(w0[g + 1], hv1, a1); b1 = fdot2_(w1[g + 1], hv1, b1);
    }
    const float ga = a0 + a1;
    const float gb = b0 + b1;
    const float sg = sigf_(ga);
    const float qv = fmaf(qc1, sigf_(qc1 * gb), qc0);
    const float ex = dppswap1_(sg * qv);
    c = fmaf(sg, c, ex);
    const float hn = qv * tanhf_(c);
    if (role) {
      hsf[par ^ 1][unit] = (_Float16)hn;
      hb[(size_t)t * (2 * H_) + unit] = (_Float16)hn;
    }
    barrier_lds_();
  };

  for (int tb = 0; tb < T_; tb += 2) {
    step(tb, 0);
    step(tb + 1, 1);
  }
}

// ---------------------------------------------------------------------------
// Emissions via MFMA (unchanged).
// ---------------------------------------------------------------------------
__global__ __launch_bounds__(256, 1)
void emis_kernel(const _Float16* __restrict__ hcat,
                 const float* __restrict__ Wp, const float* __restrict__ bp,
                 float* __restrict__ em)
{
  const int tid  = threadIdx.x;
  const int w    = tid >> 6;
  const int lane = tid & 63;
  const int lm   = lane & 15;
  const int quad = lane >> 4;

  f16x8 Bf[3][8];
  float bias[3];
  #pragma unroll
  for (int nt = 0; nt < 3; ++nt) {
    const int n = nt * 16 + lm;
    const bool valid = n < K_;
    bias[nt] = valid ? bp[n] : 0.0f;
    #pragma unroll
    for (int kt = 0; kt < 8; ++kt) {
      const int kb = kt * 32 + quad * 8;
      #pragma unroll
      for (int j = 0; j < 8; ++j)
        Bf[nt][kt][j] = valid ? (_Float16)Wp[(size_t)n * 256 + kb + j] : (_Float16)0.0f;
    }
  }

  #pragma unroll
  for (int q = 0; q < 4; ++q) {
    const int mt  = blockIdx.x * 16 + w * 4 + q;
    const int bt0 = mt * 16;

    f16x8 Af[8];
    const _Float16* ab = hcat + ((size_t)bt0 + lm) * 256;
    #pragma unroll
    for (int kt = 0; kt < 8; ++kt)
      Af[kt] = *(const f16x8*)(ab + kt * 32 + quad * 8);

    f32x4 acc[3];
    #pragma unroll
    for (int nt = 0; nt < 3; ++nt) acc[nt] = (f32x4){0.f, 0.f, 0.f, 0.f};
    #pragma unroll
    for (int kt = 0; kt < 8; ++kt)
      #pragma unroll
      for (int nt = 0; nt < 3; ++nt)
        acc[nt] = __builtin_amdgcn_mfma_f32_16x16x32_f16(Af[kt], Bf[nt][kt], acc[nt], 0, 0, 0);

    #pragma unroll
    for (int nt = 0; nt < 3; ++nt) {
      const int n = nt * 16 + lm;
      if (n < K_) {
        #pragma unroll
        for (int rg = 0; rg < 4; ++rg) {
          const int row = bt0 + quad * 4 + rg;
          em[(size_t)row * K_ + n] = acc[nt][rg] + bias[nt];
        }
      }
    }
  }
}

// ---------------------------------------------------------------------------
// Fused CRF denominator + numerator (unchanged).
// ---------------------------------------------------------------------------
__global__ __launch_bounds__(256)
void crf_dn_kernel(const float* __restrict__ em,
                   const int* __restrict__ labels, const int* __restrict__ lengths,
                   const float* __restrict__ start_t, const float* __restrict__ end_t,
                   const float* __restrict__ trans,
                   float* __restrict__ dn)
{
  const int b    = blockIdx.x;
  const int tid  = threadIdx.x;
  const int wv   = tid >> 6;
  const int lane = tid & 63;
  const int len  = lengths[b];
  const float* emb = em + (size_t)b * T_ * K_;

  __shared__ float s_num[3];
  __shared__ float s_den;

  if (wv == 0) {
    float et[K_];
    #pragma unroll
    for (int j = 0; j < K_; ++j)
      et[j] = (lane < K_) ? __expf(trans[j * K_ + lane]) : 0.0f;

    float a0 = (lane < K_) ? (start_t[lane] + emb[lane]) : -1e30f;
    float m = a0;
    #pragma unroll
    for (int off = 32; off > 0; off >>= 1) m = fmaxf(m, __shfl_xor(m, off));
    float v = __expf(a0 - m);
    float off_acc = m;

    auto ldc = [&](int t) -> float {
      const int tc = (t < len) ? t : (len - 1);
      return (lane < K_) ? emb[(size_t)tc * K_ + lane] : 0.0f;
    };

    float eA = ldc(1), eB = ldc(2), eC = ldc(3), eD = ldc(4);
    float eE = ldc(5), eF = ldc(6), eG = ldc(7), eH = ldc(8);

    auto stepden = [&](float& ereg, int tt) {
      const float emc = ereg;
      ereg = ldc(tt + 8);
      if (tt < len) {
        const float pv = v;
        float s0 = 0.f, s1 = 0.f, s2 = 0.f, s3 = 0.f;
        #pragma unroll
        for (int j = 0; j < 36; j += 4) {
          s0 = fmaf(laneb_(pv, j),     et[j],     s0);
          s1 = fmaf(laneb_(pv, j + 1), et[j + 1], s1);
          s2 = fmaf(laneb_(pv, j + 2), et[j + 2], s2);
          s3 = fmaf(laneb_(pv, j + 3), et[j + 3], s3);
        }
        s0 = fmaf(laneb_(pv, 36), et[36], s0);
        s1 = fmaf(laneb_(pv, 37), et[37], s1);
        s2 = fmaf(laneb_(pv, 38), et[38], s2);
        v = ((s0 + s1) + (s2 + s3)) * __expf(emc);
        if ((tt & 1) == 0) {
          const float sc = laneb_(v, 0);
          v *= 1.0f / sc;
          off_acc += __logf(sc);
        }
      }
    };

    for (int t = 1; t < len; t += 8) {
      stepden(eA, t);     stepden(eB, t + 1);
      stepden(eC, t + 2); stepden(eD, t + 3);
      stepden(eE, t + 4); stepden(eF, t + 5);
      stepden(eG, t + 6); stepden(eH, t + 7);
    }

    float w = (lane < K_) ? v * __expf(end_t[lane]) : 0.0f;
    #pragma unroll
    for (int off = 32; off > 0; off >>= 1) w += __shfl_xor(w, off);
    if (lane == 0) s_den = off_acc + __logf(w);
  } else {
    const int idx = tid - 64;
    float acc = 0.0f;
    for (int t = 1 + idx; t < len; t += 192) {
      const int lp = labels[b * T_ + t - 1];
      const int lc = labels[b * T_ + t];
      acc += trans[lp * K_ + lc] + emb[(size_t)t * K_ + lc];
    }
    if (tid == 64) {
      const int l0 = labels[b * T_];
      const int ll = labels[b * T_ + len - 1];
      acc += start_t[l0] + emb[l0] + end_t[ll];
    }
    #pragma unroll
    for (int off = 32; off > 0; off >>= 1) acc += __shfl_xor(acc, off);
    if (lane == 0) s_num[wv - 1] = acc;
  }
  __syncthreads();
  if (tid == 0) dn[b] = s_den - (s_num[0] + s_num[1] + s_num[2]);
}

// out = mean(dn) over the 64 batch elements (one wave).
__global__ void finalize_kernel(const float* __restrict__ dn, float* __restrict__ out)
{
  const int tid = threadIdx.x;   // 64
  float v = dn[tid];
  #pragma unroll
  for (int off = 32; off > 0; off >>= 1) v += __shfl_down(v, off);
  if (tid == 0) out[0] = v * (1.0f / 64.0f);
}

extern "C" void kernel_launch(void* const* d_in, const int* in_sizes, int n_in,
                              void* d_out, int out_size, void* d_ws, size_t ws_size,
                              hipStream_t stream)
{
  (void)in_sizes; (void)n_in; (void)out_size;
  const float* features = (const float*)d_in[0];
  const int*   lengths  = (const int*)d_in[1];
  const int*   labels   = (const int*)d_in[2];
  const float* Wih_f = (const float*)d_in[3];
  const float* Whh_f = (const float*)d_in[4];
  const float* bih_f = (const float*)d_in[5];
  const float* bhh_f = (const float*)d_in[6];
  const float* Wih_b = (const float*)d_in[7];
  const float* Whh_b = (const float*)d_in[8];
  const float* bih_b = (const float*)d_in[9];
  const float* bhh_b = (const float*)d_in[10];
  const float* Wp      = (const float*)d_in[11];
  const float* bp      = (const float*)d_in[12];
  const float* start_t = (const float*)d_in[13];
  const float* end_t   = (const float*)d_in[14];
  const float* trans   = (const float*)d_in[15];
  float* out = (float*)d_out;

  // ws layout (bytes): hcat f16 [0, 26214400) ; em f32 [26214400, +7987200) ;
  // dn 256 B ; xw f16 [34202112, +104857600) if ws is big enough.
  char* wsc = (char*)d_ws;
  _Float16* hcatH = (_Float16*)wsc;
  float*    em    = (float*)(wsc + 26214400);
  float*    dn    = (float*)(wsc + 26214400 + 7987200);
  _Float16* xwH   = (_Float16*)(wsc + 34202112);
  const bool big  = ws_size >= (size_t)34202112 + 104857600;

  if (big) {
    hipLaunchKernelGGL(xw_kernel, dim3(200), dim3(256), 0, stream,
                       features, Wih_f, Wih_b, xwH);
    hipLaunchKernelGGL(lstm_mfma_kernel, dim3(8), dim3(512), 0, stream,
                       xwH, Whh_f, Whh_b, bih_f, bhh_f, bih_b, bhh_b, hcatH);
  } else {
    hipLaunchKernelGGL(lstm_fallback_kernel, dim3(2 * B_), dim3(256), 0, stream,
                       features, Wih_f, Whh_f, bih_f, bhh_f,
                       Wih_b, Whh_b, bih_b, bhh_b, hcatH);
  }
  hipLaunchKernelGGL(emis_kernel, dim3(BT_ / 256), dim3(256), 0, stream,
                     hcatH, Wp, bp, em);
  hipLaunchKernelGGL(crf_dn_kernel, dim3(B_), dim3(256), 0, stream,
                     em, labels, lengths, start_t, end_t, trans, dn);
  hipLaunchKernelGGL(finalize_kernel, dim3(1), dim3(64), 0, stream,
                     dn, out);
}

// Round 4
// 788.826 us; speedup vs baseline: 1.4552x; 1.4552x over previous
//
#include <hip/hip_runtime.h>
#include <cstddef>
#include <cstdint>

#define B_ 64
#define T_ 800
#define D_ 80
#define H_ 128
#define K_ 39
#define BT_ (B_ * T_)   // 51200

// exp2 pre-scale constants: gates are computed as s*pre, s = -log2e (i,f,o)
// or -2*log2e (g), so activations use raw v_exp_f32 with no input multiply.
#define NL2E_  (-1.44269504f)
#define N2L2E_ (-2.88539008f)

typedef _Float16 h2_t  __attribute__((ext_vector_type(2)));
typedef _Float16 f16x8 __attribute__((ext_vector_type(8)));
typedef float    f32x4 __attribute__((ext_vector_type(4)));
typedef uint32_t u32x4 __attribute__((ext_vector_type(4)));

__device__ __forceinline__ float fdot2_(h2_t a, h2_t b, float c) {
#if __has_builtin(__builtin_amdgcn_fdot2)
  return __builtin_amdgcn_fdot2(a, b, c, false);
#else
  return c + (float)a.x * (float)b.x + (float)a.y * (float)b.y;
#endif
}

__device__ __forceinline__ h2_t asH2u_(uint32_t u) { return __builtin_bit_cast(h2_t, u); }

__device__ __forceinline__ float ex2_(float x) {
#if __has_builtin(__builtin_amdgcn_exp2f)
  return __builtin_amdgcn_exp2f(x);
#else
  return __builtin_exp2f(x);
#endif
}
__device__ __forceinline__ float rcpf_(float x) {
#if __has_builtin(__builtin_amdgcn_rcpf)
  return __builtin_amdgcn_rcpf(x);
#else
  return 1.0f / x;
#endif
}
__device__ __forceinline__ float tanhf_(float x) { return 2.0f / (1.0f + __expf(-2.0f * x)) - 1.0f; }

__device__ __forceinline__ float laneb_(float v, int lane) {
  return __builtin_bit_cast(float, __builtin_amdgcn_readlane(__builtin_bit_cast(int, v), lane));
}
__device__ __forceinline__ uint32_t lanebu_(uint32_t v, int lane) {
  return (uint32_t)__builtin_amdgcn_readlane((int)v, lane);
}

// VALU lane-pair swap via DPP quad_perm[1,0,3,2] (0xB1): lane 2k <-> 2k+1.
__device__ __forceinline__ float dppswap1_(float v) {
  return __builtin_bit_cast(float,
    __builtin_amdgcn_mov_dpp(__builtin_bit_cast(int, v), 0xB1, 0xF, 0xF, true));
}

// LDS-only barrier: waits LDS ops but does NOT drain vmem.
__device__ __forceinline__ void barrier_lds_() {
  asm volatile("s_waitcnt lgkmcnt(0)" ::: "memory");
  __builtin_amdgcn_s_barrier();
}

// lstm lane->gate-rows mapping: wave w, lane L: unit = w*32 + (L>>1),
// role = L&1. role0 owns (i,g) rows, role1 owns (f,o). DPP(1) pairs them.
__device__ __forceinline__ void rows_of_(int tid, int& unit, int& role, int& r0, int& r1) {
  const int w = tid >> 6, L = tid & 63;
  unit = w * 32 + (L >> 1);
  role = L & 1;
  r0 = role * H_ + unit;            // i (role0) or f (role1)
  r1 = 2 * H_ + role * H_ + unit;   // g (role0) or o (role1)
}

// ---------------------------------------------------------------------------
// xw via MFMA 16x16x32 f16, PAIRED output layout (R1 layout), with the gate
// rows pre-scaled by -log2e (i,f,o) / -2log2e (g) for the exp2 activations.
// ---------------------------------------------------------------------------
__global__ __launch_bounds__(256, 1)
void xw_kernel(const float* __restrict__ x,
               const float* __restrict__ Wih_f, const float* __restrict__ Wih_b,
               _Float16* __restrict__ xw)
{
  const int dir = blockIdx.x & 1;
  const int mc  = blockIdx.x >> 1;           // 0..99
  const float* W = dir ? Wih_b : Wih_f;

  const int tid  = threadIdx.x;
  const int w    = tid >> 6;
  const int lane = tid & 63;
  const int lm   = lane & 15;
  const int quad = lane >> 4;
  const int selw = w >> 1;                   // 0: i/f (.x slot), 1: g/o (.y slot)
  const int rolw = w & 1;

  f16x8 Bf[8][3];
  #pragma unroll
  for (int nt = 0; nt < 8; ++nt) {
    const int r = w * 128 + nt * 16 + lm;
    const float fac = (r >= 256 && r < 384) ? N2L2E_ : NL2E_;   // g rows: -2log2e
    #pragma unroll
    for (int kt = 0; kt < 3; ++kt) {
      const int kb = kt * 32 + quad * 8;
      #pragma unroll
      for (int j = 0; j < 8; ++j) {
        const int k = kb + j;
        Bf[nt][kt][j] = (k < D_) ? (_Float16)(fac * W[(size_t)r * D_ + k]) : (_Float16)0.0f;
      }
    }
  }

  __shared__ alignas(16) _Float16 xs[128 * 96];   // 24 KB, K padded to 96
  for (int i = tid; i < 128 * 96; i += 256) xs[i] = (_Float16)0.0f;

  for (int cc = 0; cc < 4; ++cc) {
    const int base = mc * 512 + cc * 128;
    __syncthreads();
    {
      const float4* src = (const float4*)(x + (size_t)base * D_);
      for (int i = tid; i < 128 * D_ / 4; i += 256) {
        float4 v = src[i];
        const int row = i / 20, col = (i % 20) * 4;
        h2_t p0, p1;
        p0.x = (_Float16)v.x; p0.y = (_Float16)v.y;
        p1.x = (_Float16)v.z; p1.y = (_Float16)v.w;
        uint2 pk;
        pk.x = __builtin_bit_cast(uint32_t, p0);
        pk.y = __builtin_bit_cast(uint32_t, p1);
        *(uint2*)&xs[row * 96 + col] = pk;
      }
    }
    __syncthreads();

    #pragma unroll
    for (int mt = 0; mt < 8; ++mt) {
      f16x8 Af[3];
      #pragma unroll
      for (int kt = 0; kt < 3; ++kt)
        Af[kt] = *(const f16x8*)&xs[(mt * 16 + lm) * 96 + kt * 32 + quad * 8];

      f32x4 acc[8];
      #pragma unroll
      for (int nt = 0; nt < 8; ++nt) acc[nt] = (f32x4){0.f, 0.f, 0.f, 0.f};
      #pragma unroll
      for (int kt = 0; kt < 3; ++kt)
        #pragma unroll
        for (int nt = 0; nt < 8; ++nt)
          acc[nt] = __builtin_amdgcn_mfma_f32_16x16x32_f16(Af[kt], Bf[nt][kt], acc[nt], 0, 0, 0);

      #pragma unroll
      for (int nt = 0; nt < 8; ++nt) {
        const int unit = nt * 16 + lm;
        const int ptid = (unit >> 5) * 64 + (unit & 31) * 2 + rolw;
        #pragma unroll
        for (int rg = 0; rg < 4; ++rg) {
          const int bt = base + mt * 16 + quad * 4 + rg;
          xw[((size_t)dir * BT_ + bt) * 512 + ptid * 2 + selw] = (_Float16)acc[nt][rg];
        }
      }
    }
  }
}

// ---------------------------------------------------------------------------
// Recurrent LSTM (R1 structure; R4 changes):
//  (1) 8 accumulation chains (depth 16) in the h-dot instead of 4 (depth 32).
//  (2) exp2-prescaled weights/bias -> raw v_exp activations (no input muls).
//  (3) running-offset addressing for xw prefetch and hcat store.
// ---------------------------------------------------------------------------
template<int USE_XW>
__global__ __launch_bounds__(256, 1)
void lstm_kernel(const float* __restrict__ x,
                 const float* __restrict__ Wih_f, const float* __restrict__ Whh_f,
                 const float* __restrict__ bih_f, const float* __restrict__ bhh_f,
                 const float* __restrict__ Wih_b, const float* __restrict__ Whh_b,
                 const float* __restrict__ bih_b, const float* __restrict__ bhh_b,
                 const _Float16* __restrict__ xw,
                 _Float16* __restrict__ hcat)
{
  const int bb  = blockIdx.x & 63;
  const int dir = blockIdx.x >> 6;
  const float* Whh = dir ? Whh_b : Whh_f;
  const float* Wih = dir ? Wih_b : Wih_f;
  const float* bih = dir ? bih_b : bih_f;
  const float* bhh = dir ? bhh_b : bhh_f;

  const int tid  = threadIdx.x;
  const int lane = tid & 63;
  int unit, role, r0, r1; rows_of_(tid, unit, role, r0, r1);
  // row scales: r0 is i/f -> -log2e; r1 is g (role0, -2log2e) or o (role1).
  const float s0 = NL2E_;
  const float s1 = role ? NL2E_ : N2L2E_;
  // qv = (1 + qk2*eb) * rcp(1+eb): role0 tanh(g) (qk2=-1), role1 sig(o) (qk2=0).
  const float qk2 = role ? 0.0f : -1.0f;

  h2_t w0[64], w1[64];
  #pragma unroll
  for (int j = 0; j < 64; ++j) {
    float2 a = *(const float2*)(Whh + (size_t)r0 * H_ + 2 * j);
    float2 d = *(const float2*)(Whh + (size_t)r1 * H_ + 2 * j);
    w0[j].x = (_Float16)(s0 * a.x); w0[j].y = (_Float16)(s0 * a.y);
    w1[j].x = (_Float16)(s1 * d.x); w1[j].y = (_Float16)(s1 * d.y);
  }
  h2_t wx0[40], wx1[40];
  if (!USE_XW) {
    #pragma unroll
    for (int i = 0; i < 40; ++i) {
      float2 a = *(const float2*)(Wih + (size_t)r0 * D_ + 2 * i);
      float2 d = *(const float2*)(Wih + (size_t)r1 * D_ + 2 * i);
      wx0[i].x = (_Float16)(s0 * a.x); wx0[i].y = (_Float16)(s0 * a.y);
      wx1[i].x = (_Float16)(s1 * d.x); wx1[i].y = (_Float16)(s1 * d.y);
    }
  }
  const float bias0 = s0 * (bih[r0] + bhh[r0]);
  const float bias1 = s1 * (bih[r1] + bhh[r1]);

  __shared__ alignas(16) _Float16 hsf[2][H_];  // double-buffered h
  __shared__ uint32_t xs2[2][64];              // fallback x staging

  if (tid < H_) hsf[0][tid] = (_Float16)0.0f;
  if (!USE_XW && tid < 64) { xs2[0][tid] = 0u; xs2[1][tid] = 0u; }
  float c = 0.0f;   // role1 owns cell state of its unit

  const uint32_t* xwdu = (const uint32_t*)xw + ((size_t)dir * BT_ + (size_t)bb * T_) * 256;
  const float*    xb   = x + (size_t)bb * T_ * D_;
  _Float16*       hb   = hcat + (size_t)bb * T_ * (2 * H_) + dir * H_;

  // running pointers/offsets (advance by a constant per step)
  _Float16* hbp = hb + (size_t)(dir ? (T_ - 1) : 0) * (2 * H_);
  const ptrdiff_t hstep = dir ? -(2 * H_) : (2 * H_);
  int xoff = (dir ? (T_ - 3) : 2) * 256 + tid;     // prefetch offset for ttc=2
  const int xstep = dir ? -256 : 256;

  uint32_t xwA = 0u, xwB = 0u;
  h2_t xpend; xpend.x = (_Float16)0.f; xpend.y = (_Float16)0.f;
  {
    const int tq0 = dir ? (T_ - 1) : 0;
    const int tq1 = dir ? (T_ - 2) : 1;
    if (USE_XW) {
      xwA = xwdu[(size_t)tq0 * 256 + tid];
      xwB = xwdu[(size_t)tq1 * 256 + tid];
    } else if (tid < 40) {
      float2 v0 = *(const float2*)(xb + (size_t)tq0 * D_ + 2 * tid);
      h2_t p; p.x = (_Float16)v0.x; p.y = (_Float16)v0.y;
      xs2[0][tid] = __builtin_bit_cast(uint32_t, p);
      float2 v1 = *(const float2*)(xb + (size_t)tq1 * D_ + 2 * tid);
      xpend.x = (_Float16)v1.x; xpend.y = (_Float16)v1.y;
    }
  }
  __syncthreads();

  auto step = [&](int tt, int par, uint32_t& xwreg) {
    float a0, a1, a2, a3, b0, b1, b2, b3;
    if (USE_XW) {
      const h2_t xv = asH2u_(xwreg);
      a0 = bias0 + (float)xv.x;
      b0 = bias1 + (float)xv.y;
      a1 = a2 = a3 = 0.f; b1 = b2 = b3 = 0.f;
      xwreg = xwdu[xoff];                         // prefetch; consumed 2 steps later
    } else {
      a0 = bias0; b0 = bias1;
      a1 = a2 = a3 = 0.f; b1 = b2 = b3 = 0.f;
      if (tid < 40) {
        xs2[par ^ 1][tid] = __builtin_bit_cast(uint32_t, xpend);
        const int ttc = (tt + 2 < T_) ? (tt + 2) : (T_ - 1);
        const int tq2 = dir ? (T_ - 1 - ttc) : ttc;
        float2 v = *(const float2*)(xb + (size_t)tq2 * D_ + 2 * tid);
        xpend.x = (_Float16)v.x; xpend.y = (_Float16)v.y;
      }
      uint32_t xreg = xs2[par][lane];
      #pragma unroll
      for (int j = 0; j < 40; j += 4) {
        h2_t q0 = asH2u_(lanebu_(xreg, j));
        h2_t q1 = asH2u_(lanebu_(xreg, j + 1));
        h2_t q2 = asH2u_(lanebu_(xreg, j + 2));
        h2_t q3 = asH2u_(lanebu_(xreg, j + 3));
        a0 = fdot2_(wx0[j],     q0, a0); b0 = fdot2_(wx1[j],     q0, b0);
        a1 = fdot2_(wx0[j + 1], q1, a1); b1 = fdot2_(wx1[j + 1], q1, b1);
        a2 = fdot2_(wx0[j + 2], q2, a2); b2 = fdot2_(wx1[j + 2], q2, b2);
        a3 = fdot2_(wx0[j + 3], q3, a3); b3 = fdot2_(wx1[j + 3], q3, b3);
      }
    }

    // h @ Whh^T via uniform-address LDS broadcasts, interleaved (compiler
    // pipelines with partial lgkmcnt waits). 8 chains, depth 16.
    const u32x4* hq = (const u32x4*)hsf[par];
    #pragma unroll
    for (int g = 0; g < 16; ++g) {
      const u32x4 hv = hq[g];
      a0 = fdot2_(w0[4 * g + 0], asH2u_(hv[0]), a0);
      b0 = fdot2_(w1[4 * g + 0], asH2u_(hv[0]), b0);
      a1 = fdot2_(w0[4 * g + 1], asH2u_(hv[1]), a1);
      b1 = fdot2_(w1[4 * g + 1], asH2u_(hv[1]), b1);
      a2 = fdot2_(w0[4 * g + 2], asH2u_(hv[2]), a2);
      b2 = fdot2_(w1[4 * g + 2], asH2u_(hv[2]), b2);
      a3 = fdot2_(w0[4 * g + 3], asH2u_(hv[3]), a3);
      b3 = fdot2_(w1[4 * g + 3], asH2u_(hv[3]), b3);
    }
    const float ga = (a0 + a1) + (a2 + a3);   // -log2e * (i|f pre-activation)
    const float gb = (b0 + b1) + (b2 + b3);   // -2log2e*g (role0) | -log2e*o (role1)

    // activations on exp2-prescaled gates:
    // sg = sig(i|f) = rcp(1+exp2(ga)); qv = tanh(g) (role0) | sig(o) (role1).
    const float ea = ex2_(ga);
    const float sg = rcpf_(1.0f + ea);
    const float gbc = fminf(fmaxf(gb, -34.6f), 34.6f);
    const float eb = ex2_(gbc);
    const float qv = fmaf(qk2, eb, 1.0f) * rcpf_(1.0f + eb);
    const float ex = dppswap1_(sg * qv);      // role1 receives p = sig(i)*tanh(g)
    c = fmaf(sg, c, ex);                      // role1: sig(f)*c + p (role0 benign)
    const float hn = qv * tanhf_(c);          // role1: sig(o)*tanh(c)
    if (role) {
      hsf[par ^ 1][unit] = (_Float16)hn;
      hbp[unit] = (_Float16)hn;               // async store, never drained
    }
    hbp += hstep;
    if (tt + 3 < T_) xoff += xstep;           // wave-uniform clamp-advance
    barrier_lds_();
  };

  for (int tb = 0; tb < T_; tb += 2) {
    step(tb,     0, xwA);
    step(tb + 1, 1, xwB);
  }
}

// ---------------------------------------------------------------------------
// Emissions via MFMA (unchanged).
// ---------------------------------------------------------------------------
__global__ __launch_bounds__(256, 1)
void emis_kernel(const _Float16* __restrict__ hcat,
                 const float* __restrict__ Wp, const float* __restrict__ bp,
                 float* __restrict__ em)
{
  const int tid  = threadIdx.x;
  const int w    = tid >> 6;
  const int lane = tid & 63;
  const int lm   = lane & 15;
  const int quad = lane >> 4;

  f16x8 Bf[3][8];
  float bias[3];
  #pragma unroll
  for (int nt = 0; nt < 3; ++nt) {
    const int n = nt * 16 + lm;
    const bool valid = n < K_;
    bias[nt] = valid ? bp[n] : 0.0f;
    #pragma unroll
    for (int kt = 0; kt < 8; ++kt) {
      const int kb = kt * 32 + quad * 8;
      #pragma unroll
      for (int j = 0; j < 8; ++j)
        Bf[nt][kt][j] = valid ? (_Float16)Wp[(size_t)n * 256 + kb + j] : (_Float16)0.0f;
    }
  }

  #pragma unroll
  for (int q = 0; q < 4; ++q) {
    const int mt  = blockIdx.x * 16 + w * 4 + q;
    const int bt0 = mt * 16;

    f16x8 Af[8];
    const _Float16* ab = hcat + ((size_t)bt0 + lm) * 256;
    #pragma unroll
    for (int kt = 0; kt < 8; ++kt)
      Af[kt] = *(const f16x8*)(ab + kt * 32 + quad * 8);

    f32x4 acc[3];
    #pragma unroll
    for (int nt = 0; nt < 3; ++nt) acc[nt] = (f32x4){0.f, 0.f, 0.f, 0.f};
    #pragma unroll
    for (int kt = 0; kt < 8; ++kt)
      #pragma unroll
      for (int nt = 0; nt < 3; ++nt)
        acc[nt] = __builtin_amdgcn_mfma_f32_16x16x32_f16(Af[kt], Bf[nt][kt], acc[nt], 0, 0, 0);

    #pragma unroll
    for (int nt = 0; nt < 3; ++nt) {
      const int n = nt * 16 + lm;
      if (n < K_) {
        #pragma unroll
        for (int rg = 0; rg < 4; ++rg) {
          const int row = bt0 + quad * 4 + rg;
          em[(size_t)row * K_ + n] = acc[nt][rg] + bias[nt];
        }
      }
    }
  }
}

// ---------------------------------------------------------------------------
// Fused CRF denominator + numerator.
// R4: the 39-wide broadcast MAC per step now goes through LDS uniform reads
// (1 ds_write_b32 + 10 float4 broadcast loads) instead of 39 v_readlane
// broadcasts (SGPR-write -> VALU-read hazards each).
// ---------------------------------------------------------------------------
__global__ __launch_bounds__(256)
void crf_dn_kernel(const float* __restrict__ em,
                   const int* __restrict__ labels, const int* __restrict__ lengths,
                   const float* __restrict__ start_t, const float* __restrict__ end_t,
                   const float* __restrict__ trans,
                   float* __restrict__ dn)
{
  const int b    = blockIdx.x;
  const int tid  = threadIdx.x;
  const int wv   = tid >> 6;
  const int lane = tid & 63;
  const int len  = lengths[b];
  const float* emb = em + (size_t)b * T_ * K_;

  __shared__ float s_num[3];
  __shared__ float s_den;
  __shared__ alignas(16) float vbuf[64];   // wave-0 alpha broadcast buffer

  if (wv == 0) {
    // ---------------- serial denominator, 1 wave ----------------
    float et[K_];
    #pragma unroll
    for (int j = 0; j < K_; ++j)
      et[j] = (lane < K_) ? __expf(trans[j * K_ + lane]) : 0.0f;

    float a0 = (lane < K_) ? (start_t[lane] + emb[lane]) : -1e30f;
    float m = a0;
    #pragma unroll
    for (int off = 32; off > 0; off >>= 1) m = fmaxf(m, __shfl_xor(m, off));
    float v = __expf(a0 - m);           // lanes >= 39 -> 0
    float off_acc = m;
    vbuf[lane] = 0.0f;                  // init (lanes >= 39 stay 0 forever)

    auto ldc = [&](int t) -> float {
      const int tc = (t < len) ? t : (len - 1);
      return (lane < K_) ? emb[(size_t)tc * K_ + lane] : 0.0f;
    };

    // 8 NAMED pipeline registers — no rotation moves.
    float eA = ldc(1), eB = ldc(2), eC = ldc(3), eD = ldc(4);
    float eE = ldc(5), eF = ldc(6), eG = ldc(7), eH = ldc(8);

    auto stepden = [&](float& ereg, int tt) {
      const float emc = ereg;
      ereg = ldc(tt + 8);               // reload same named reg for tt+8
      if (tt < len) {                   // wave-uniform guard
        vbuf[lane] = v;                 // publish alpha to LDS
        asm volatile("s_waitcnt lgkmcnt(0)" ::: "memory");   // 1-wave ordering
        const float4* vq = (const float4*)vbuf;
        float s0 = 0.f, s1 = 0.f, s2 = 0.f, s3 = 0.f;
        #pragma unroll
        for (int g = 0; g < 9; ++g) {   // j = 0..35
          const float4 q = vq[g];
          s0 = fmaf(q.x, et[4 * g],     s0);
          s1 = fmaf(q.y, et[4 * g + 1], s1);
          s2 = fmaf(q.z, et[4 * g + 2], s2);
          s3 = fmaf(q.w, et[4 * g + 3], s3);
        }
        const float4 q9 = vq[9];        // j = 36..38 (vbuf[39] is always 0)
        s0 = fmaf(q9.x, et[36], s0);
        s1 = fmaf(q9.y, et[37], s1);
        s2 = fmaf(q9.z, et[38], s2);
        v = ((s0 + s1) + (s2 + s3)) * __expf(emc);
        if ((tt & 1) == 0) {            // VALU-only renorm (all terms > 0)
          const float sc = laneb_(v, 0);
          v *= 1.0f / sc;
          off_acc += __logf(sc);
        }
      }
    };

    for (int t = 1; t < len; t += 8) {
      stepden(eA, t);     stepden(eB, t + 1);
      stepden(eC, t + 2); stepden(eD, t + 3);
      stepden(eE, t + 4); stepden(eF, t + 5);
      stepden(eG, t + 6); stepden(eH, t + 7);
    }

    float w = (lane < K_) ? v * __expf(end_t[lane]) : 0.0f;
    #pragma unroll
    for (int off = 32; off > 0; off >>= 1) w += __shfl_xor(w, off);
    if (lane == 0) s_den = off_acc + __logf(w);
  } else {
    // ---------------- parallel numerator, 3 waves ----------------
    const int idx = tid - 64;           // 0..191
    float acc = 0.0f;
    for (int t = 1 + idx; t < len; t += 192) {
      const int lp = labels[b * T_ + t - 1];
      const int lc = labels[b * T_ + t];
      acc += trans[lp * K_ + lc] + emb[(size_t)t * K_ + lc];
    }
    if (tid == 64) {                    // edge terms on one lane
      const int l0 = labels[b * T_];
      const int ll = labels[b * T_ + len - 1];
      acc += start_t[l0] + emb[l0] + end_t[ll];
    }
    #pragma unroll
    for (int off = 32; off > 0; off >>= 1) acc += __shfl_xor(acc, off);
    if (lane == 0) s_num[wv - 1] = acc;
  }
  __syncthreads();
  if (tid == 0) dn[b] = s_den - (s_num[0] + s_num[1] + s_num[2]);
}

// out = mean(dn) over the 64 batch elements (one wave).
__global__ void finalize_kernel(const float* __restrict__ dn, float* __restrict__ out)
{
  const int tid = threadIdx.x;   // 64
  float v = dn[tid];
  #pragma unroll
  for (int off = 32; off > 0; off >>= 1) v += __shfl_down(v, off);
  if (tid == 0) out[0] = v * (1.0f / 64.0f);
}

extern "C" void kernel_launch(void* const* d_in, const int* in_sizes, int n_in,
                              void* d_out, int out_size, void* d_ws, size_t ws_size,
                              hipStream_t stream)
{
  (void)in_sizes; (void)n_in; (void)out_size;
  const float* features = (const float*)d_in[0];
  const int*   lengths  = (const int*)d_in[1];
  const int*   labels   = (const int*)d_in[2];
  const float* Wih_f = (const float*)d_in[3];
  const float* Whh_f = (const float*)d_in[4];
  const float* bih_f = (const float*)d_in[5];
  const float* bhh_f = (const float*)d_in[6];
  const float* Wih_b = (const float*)d_in[7];
  const float* Whh_b = (const float*)d_in[8];
  const float* bih_b = (const float*)d_in[9];
  const float* bhh_b = (const float*)d_in[10];
  const float* Wp      = (const float*)d_in[11];
  const float* bp      = (const float*)d_in[12];
  const float* start_t = (const float*)d_in[13];
  const float* end_t   = (const float*)d_in[14];
  const float* trans   = (const float*)d_in[15];
  float* out = (float*)d_out;

  // ws layout (bytes): hcat f16 [0, 26214400) ; em f32 [26214400, +7987200) ;
  // dn 256 B ; xw f16 [34202112, +104857600) if ws is big enough.
  char* wsc = (char*)d_ws;
  _Float16* hcatH = (_Float16*)wsc;
  float*    em    = (float*)(wsc + 26214400);
  float*    dn    = (float*)(wsc + 26214400 + 7987200);
  _Float16* xwH   = (_Float16*)(wsc + 34202112);
  const bool big  = ws_size >= (size_t)34202112 + 104857600;

  if (big) {
    hipLaunchKernelGGL(xw_kernel, dim3(200), dim3(256), 0, stream,
                       features, Wih_f, Wih_b, xwH);
    hipLaunchKernelGGL((lstm_kernel<1>), dim3(2 * B_), dim3(256), 0, stream,
                       features, Wih_f, Whh_f, bih_f, bhh_f,
                       Wih_b, Whh_b, bih_b, bhh_b, xwH, hcatH);
  } else {
    hipLaunchKernelGGL((lstm_kernel<0>), dim3(2 * B_), dim3(256), 0, stream,
                       features, Wih_f, Whh_f, bih_f, bhh_f,
                       Wih_b, Whh_b, bih_b, bhh_b, xwH, hcatH);
  }
  hipLaunchKernelGGL(emis_kernel, dim3(BT_ / 256), dim3(256), 0, stream,
                     hcatH, Wp, bp, em);
  hipLaunchKernelGGL(crf_dn_kernel, dim3(B_), dim3(256), 0, stream,
                     em, labels, lengths, start_t, end_t, trans, dn);
  hipLaunchKernelGGL(finalize_kernel, dim3(1), dim3(64), 0, stream,
                     dn, out);
}

// Round 5
// 748.970 us; speedup vs baseline: 1.5326x; 1.0532x over previous
//
#include <hip/hip_runtime.h>
#include <cstddef>
#include <cstdint>

#define B_ 64
#define T_ 800
#define D_ 80
#define H_ 128
#define K_ 39
#define BT_ (B_ * T_)   // 51200

// exp2 pre-scale constants: gates are computed as s*pre, s = -log2e (i,f,o)
// or -2*log2e (g), so activations use raw v_exp_f32 with no input multiply.
#define NL2E_  (-1.44269504f)
#define N2L2E_ (-2.88539008f)

typedef _Float16 h2_t  __attribute__((ext_vector_type(2)));
typedef _Float16 f16x8 __attribute__((ext_vector_type(8)));
typedef float    f32x4 __attribute__((ext_vector_type(4)));
typedef uint32_t u32x4 __attribute__((ext_vector_type(4)));

__device__ __forceinline__ float fdot2_(h2_t a, h2_t b, float c) {
#if __has_builtin(__builtin_amdgcn_fdot2)
  return __builtin_amdgcn_fdot2(a, b, c, false);
#else
  return c + (float)a.x * (float)b.x + (float)a.y * (float)b.y;
#endif
}

__device__ __forceinline__ h2_t asH2u_(uint32_t u) { return __builtin_bit_cast(h2_t, u); }

__device__ __forceinline__ float ex2_(float x) {
#if __has_builtin(__builtin_amdgcn_exp2f)
  return __builtin_amdgcn_exp2f(x);
#else
  return __builtin_exp2f(x);
#endif
}
__device__ __forceinline__ float rcpf_(float x) {
#if __has_builtin(__builtin_amdgcn_rcpf)
  return __builtin_amdgcn_rcpf(x);
#else
  return 1.0f / x;
#endif
}
__device__ __forceinline__ float tanhf_(float x) { return 2.0f / (1.0f + __expf(-2.0f * x)) - 1.0f; }

__device__ __forceinline__ float laneb_(float v, int lane) {
  return __builtin_bit_cast(float, __builtin_amdgcn_readlane(__builtin_bit_cast(int, v), lane));
}
__device__ __forceinline__ uint32_t lanebu_(uint32_t v, int lane) {
  return (uint32_t)__builtin_amdgcn_readlane((int)v, lane);
}

// VALU lane-pair swap via DPP quad_perm[1,0,3,2] (0xB1): lane 2k <-> 2k+1.
__device__ __forceinline__ float dppswap1_(float v) {
  return __builtin_bit_cast(float,
    __builtin_amdgcn_mov_dpp(__builtin_bit_cast(int, v), 0xB1, 0xF, 0xF, true));
}

// Generic quad_perm DPP move on a u32 (CTRL: 0xB1=xor1, 0x4E=xor2, 0x1B=xor3).
template<int CTRL>
__device__ __forceinline__ uint32_t dppu_(uint32_t v) {
  return (uint32_t)__builtin_amdgcn_mov_dpp((int)v, CTRL, 0xF, 0xF, true);
}

// LDS-only barrier: waits LDS ops but does NOT drain vmem.
__device__ __forceinline__ void barrier_lds_() {
  asm volatile("s_waitcnt lgkmcnt(0)" ::: "memory");
  __builtin_amdgcn_s_barrier();
}

// lstm lane->gate-rows mapping: wave w, lane L: unit = w*32 + (L>>1),
// role = L&1. role0 owns (i,g) rows, role1 owns (f,o). DPP(1) pairs them.
__device__ __forceinline__ void rows_of_(int tid, int& unit, int& role, int& r0, int& r1) {
  const int w = tid >> 6, L = tid & 63;
  unit = w * 32 + (L >> 1);
  role = L & 1;
  r0 = role * H_ + unit;            // i (role0) or f (role1)
  r1 = 2 * H_ + role * H_ + unit;   // g (role0) or o (role1)
}

// ---------------------------------------------------------------------------
// xw via MFMA 16x16x32 f16, PAIRED output layout, gate rows pre-scaled by
// -log2e (i,f,o) / -2log2e (g) for the exp2 activations. (Unchanged from R4.)
// ---------------------------------------------------------------------------
__global__ __launch_bounds__(256, 1)
void xw_kernel(const float* __restrict__ x,
               const float* __restrict__ Wih_f, const float* __restrict__ Wih_b,
               _Float16* __restrict__ xw)
{
  const int dir = blockIdx.x & 1;
  const int mc  = blockIdx.x >> 1;           // 0..99
  const float* W = dir ? Wih_b : Wih_f;

  const int tid  = threadIdx.x;
  const int w    = tid >> 6;
  const int lane = tid & 63;
  const int lm   = lane & 15;
  const int quad = lane >> 4;
  const int selw = w >> 1;                   // 0: i/f (.x slot), 1: g/o (.y slot)
  const int rolw = w & 1;

  f16x8 Bf[8][3];
  #pragma unroll
  for (int nt = 0; nt < 8; ++nt) {
    const int r = w * 128 + nt * 16 + lm;
    const float fac = (r >= 256 && r < 384) ? N2L2E_ : NL2E_;   // g rows: -2log2e
    #pragma unroll
    for (int kt = 0; kt < 3; ++kt) {
      const int kb = kt * 32 + quad * 8;
      #pragma unroll
      for (int j = 0; j < 8; ++j) {
        const int k = kb + j;
        Bf[nt][kt][j] = (k < D_) ? (_Float16)(fac * W[(size_t)r * D_ + k]) : (_Float16)0.0f;
      }
    }
  }

  __shared__ alignas(16) _Float16 xs[128 * 96];   // 24 KB, K padded to 96
  for (int i = tid; i < 128 * 96; i += 256) xs[i] = (_Float16)0.0f;

  for (int cc = 0; cc < 4; ++cc) {
    const int base = mc * 512 + cc * 128;
    __syncthreads();
    {
      const float4* src = (const float4*)(x + (size_t)base * D_);
      for (int i = tid; i < 128 * D_ / 4; i += 256) {
        float4 v = src[i];
        const int row = i / 20, col = (i % 20) * 4;
        h2_t p0, p1;
        p0.x = (_Float16)v.x; p0.y = (_Float16)v.y;
        p1.x = (_Float16)v.z; p1.y = (_Float16)v.w;
        uint2 pk;
        pk.x = __builtin_bit_cast(uint32_t, p0);
        pk.y = __builtin_bit_cast(uint32_t, p1);
        *(uint2*)&xs[row * 96 + col] = pk;
      }
    }
    __syncthreads();

    #pragma unroll
    for (int mt = 0; mt < 8; ++mt) {
      f16x8 Af[3];
      #pragma unroll
      for (int kt = 0; kt < 3; ++kt)
        Af[kt] = *(const f16x8*)&xs[(mt * 16 + lm) * 96 + kt * 32 + quad * 8];

      f32x4 acc[8];
      #pragma unroll
      for (int nt = 0; nt < 8; ++nt) acc[nt] = (f32x4){0.f, 0.f, 0.f, 0.f};
      #pragma unroll
      for (int kt = 0; kt < 3; ++kt)
        #pragma unroll
        for (int nt = 0; nt < 8; ++nt)
          acc[nt] = __builtin_amdgcn_mfma_f32_16x16x32_f16(Af[kt], Bf[nt][kt], acc[nt], 0, 0, 0);

      #pragma unroll
      for (int nt = 0; nt < 8; ++nt) {
        const int unit = nt * 16 + lm;
        const int ptid = (unit >> 5) * 64 + (unit & 31) * 2 + rolw;
        #pragma unroll
        for (int rg = 0; rg < 4; ++rg) {
          const int bt = base + mt * 16 + quad * 4 + rg;
          xw[((size_t)dir * BT_ + bt) * 512 + ptid * 2 + selw] = (_Float16)acc[nt][rg];
        }
      }
    }
  }
}

// ---------------------------------------------------------------------------
// Recurrent LSTM. R5 change: h-broadcast reads 16 uniform ds_read_b128 ->
// 4 per-lane chunk reads + 48 v_mov_dpp quad_perm exchanges (xor1/2/3).
// Lane L owns chunk Q=L&3 of h; lane L^r owns chunk Q^r, so one DPP per u32
// delivers chunk Q^r to every lane. Weights are loaded in Q-permuted order so
// the fdot2 loop stays lane-uniform. LDS return-pipe traffic: 64 -> 16
// instr/step/CU. Everything else identical to R4.
// ---------------------------------------------------------------------------
template<int USE_XW>
__global__ __launch_bounds__(256, 1)
void lstm_kernel(const float* __restrict__ x,
                 const float* __restrict__ Wih_f, const float* __restrict__ Whh_f,
                 const float* __restrict__ bih_f, const float* __restrict__ bhh_f,
                 const float* __restrict__ Wih_b, const float* __restrict__ Whh_b,
                 const float* __restrict__ bih_b, const float* __restrict__ bhh_b,
                 const _Float16* __restrict__ xw,
                 _Float16* __restrict__ hcat)
{
  const int bb  = blockIdx.x & 63;
  const int dir = blockIdx.x >> 6;
  const float* Whh = dir ? Whh_b : Whh_f;
  const float* Wih = dir ? Wih_b : Wih_f;
  const float* bih = dir ? bih_b : bih_f;
  const float* bhh = dir ? bhh_b : bhh_f;

  const int tid  = threadIdx.x;
  const int lane = tid & 63;
  const int Q    = lane & 3;                 // h-chunk this lane reads
  int unit, role, r0, r1; rows_of_(tid, unit, role, r0, r1);
  // row scales: r0 is i/f -> -log2e; r1 is g (role0, -2log2e) or o (role1).
  const float s0 = NL2E_;
  const float s1 = role ? NL2E_ : N2L2E_;
  // qv = (1 + qk2*eb) * rcp(1+eb): role0 tanh(g) (qk2=-1), role1 sig(o) (qk2=0).
  const float qk2 = role ? 0.0f : -1.0f;

  // Whh weights in Q-PERMUTED order: wp[r*16+jj] pairs with h2-pair
  // (Q^r)*16+jj, consumed in round r of the DPP exchange.
  h2_t wp0[64], wp1[64];
  #pragma unroll
  for (int r = 0; r < 4; ++r) {
    const int ch = Q ^ r;
    #pragma unroll
    for (int jj = 0; jj < 16; ++jj) {
      const int j = ch * 16 + jj;            // h2-pair index 0..63
      float2 a = *(const float2*)(Whh + (size_t)r0 * H_ + 2 * j);
      float2 d = *(const float2*)(Whh + (size_t)r1 * H_ + 2 * j);
      wp0[r * 16 + jj].x = (_Float16)(s0 * a.x); wp0[r * 16 + jj].y = (_Float16)(s0 * a.y);
      wp1[r * 16 + jj].x = (_Float16)(s1 * d.x); wp1[r * 16 + jj].y = (_Float16)(s1 * d.y);
    }
  }
  h2_t wx0[40], wx1[40];
  if (!USE_XW) {
    #pragma unroll
    for (int i = 0; i < 40; ++i) {
      float2 a = *(const float2*)(Wih + (size_t)r0 * D_ + 2 * i);
      float2 d = *(const float2*)(Wih + (size_t)r1 * D_ + 2 * i);
      wx0[i].x = (_Float16)(s0 * a.x); wx0[i].y = (_Float16)(s0 * a.y);
      wx1[i].x = (_Float16)(s1 * d.x); wx1[i].y = (_Float16)(s1 * d.y);
    }
  }
  const float bias0 = s0 * (bih[r0] + bhh[r0]);
  const float bias1 = s1 * (bih[r1] + bhh[r1]);

  __shared__ alignas(16) _Float16 hsf[2][H_];  // double-buffered h
  __shared__ uint32_t xs2[2][64];              // fallback x staging

  if (tid < H_) hsf[0][tid] = (_Float16)0.0f;
  if (!USE_XW && tid < 64) { xs2[0][tid] = 0u; xs2[1][tid] = 0u; }
  float c = 0.0f;   // role1 owns cell state of its unit

  const uint32_t* xwdu = (const uint32_t*)xw + ((size_t)dir * BT_ + (size_t)bb * T_) * 256;
  const float*    xb   = x + (size_t)bb * T_ * D_;
  _Float16*       hb   = hcat + (size_t)bb * T_ * (2 * H_) + dir * H_;

  // running pointers/offsets (advance by a constant per step)
  _Float16* hbp = hb + (size_t)(dir ? (T_ - 1) : 0) * (2 * H_);
  const ptrdiff_t hstep = dir ? -(2 * H_) : (2 * H_);
  int xoff = (dir ? (T_ - 3) : 2) * 256 + tid;     // prefetch offset for ttc=2
  const int xstep = dir ? -256 : 256;

  uint32_t xwA = 0u, xwB = 0u;
  h2_t xpend; xpend.x = (_Float16)0.f; xpend.y = (_Float16)0.f;
  {
    const int tq0 = dir ? (T_ - 1) : 0;
    const int tq1 = dir ? (T_ - 2) : 1;
    if (USE_XW) {
      xwA = xwdu[(size_t)tq0 * 256 + tid];
      xwB = xwdu[(size_t)tq1 * 256 + tid];
    } else if (tid < 40) {
      float2 v0 = *(const float2*)(xb + (size_t)tq0 * D_ + 2 * tid);
      h2_t p; p.x = (_Float16)v0.x; p.y = (_Float16)v0.y;
      xs2[0][tid] = __builtin_bit_cast(uint32_t, p);
      float2 v1 = *(const float2*)(xb + (size_t)tq1 * D_ + 2 * tid);
      xpend.x = (_Float16)v1.x; xpend.y = (_Float16)v1.y;
    }
  }
  __syncthreads();

  auto step = [&](int tt, int par, uint32_t& xwreg) {
    float a[4], b[4];
    if (USE_XW) {
      const h2_t xv = asH2u_(xwreg);
      a[0] = bias0 + (float)xv.x;
      b[0] = bias1 + (float)xv.y;
      a[1] = a[2] = a[3] = 0.f; b[1] = b[2] = b[3] = 0.f;
      xwreg = xwdu[xoff];                         // prefetch; consumed 2 steps later
    } else {
      a[0] = bias0; b[0] = bias1;
      a[1] = a[2] = a[3] = 0.f; b[1] = b[2] = b[3] = 0.f;
      if (tid < 40) {
        xs2[par ^ 1][tid] = __builtin_bit_cast(uint32_t, xpend);
        const int ttc = (tt + 2 < T_) ? (tt + 2) : (T_ - 1);
        const int tq2 = dir ? (T_ - 1 - ttc) : ttc;
        float2 v = *(const float2*)(xb + (size_t)tq2 * D_ + 2 * tid);
        xpend.x = (_Float16)v.x; xpend.y = (_Float16)v.y;
      }
      uint32_t xreg = xs2[par][lane];
      #pragma unroll
      for (int j = 0; j < 40; j += 4) {
        h2_t q0 = asH2u_(lanebu_(xreg, j));
        h2_t q1 = asH2u_(lanebu_(xreg, j + 1));
        h2_t q2 = asH2u_(lanebu_(xreg, j + 2));
        h2_t q3 = asH2u_(lanebu_(xreg, j + 3));
        a[0] = fdot2_(wx0[j],     q0, a[0]); b[0] = fdot2_(wx1[j],     q0, b[0]);
        a[1] = fdot2_(wx0[j + 1], q1, a[1]); b[1] = fdot2_(wx1[j + 1], q1, b[1]);
        a[2] = fdot2_(wx0[j + 2], q2, a[2]); b[2] = fdot2_(wx1[j + 2], q2, b[2]);
        a[3] = fdot2_(wx0[j + 3], q3, a[3]); b[3] = fdot2_(wx1[j + 3], q3, b[3]);
      }
    }

    // h @ Whh^T: lane reads ONLY its chunk Q (4 per-lane b128), other chunks
    // arrive via quad_perm DPP (VALU pipe, not LDS pipe).
    const u32x4* hq = (const u32x4*)hsf[par];
    u32x4 ovr[4];
    #pragma unroll
    for (int reg = 0; reg < 4; ++reg) ovr[reg] = hq[Q * 4 + reg];

    u32x4 x1[4], x2[4], x3[4];
    #pragma unroll
    for (int reg = 0; reg < 4; ++reg) {
      #pragma unroll
      for (int e = 0; e < 4; ++e) {
        x1[reg][e] = dppu_<0xB1>(ovr[reg][e]);   // chunk Q^1
        x2[reg][e] = dppu_<0x4E>(ovr[reg][e]);   // chunk Q^2
        x3[reg][e] = dppu_<0x1B>(ovr[reg][e]);   // chunk Q^3
      }
    }

    #define HROUND_(HV, RB)                                        \
      _Pragma("unroll")                                            \
      for (int reg = 0; reg < 4; ++reg) {                          \
        _Pragma("unroll")                                          \
        for (int e = 0; e < 4; ++e) {                              \
          const h2_t hh = asH2u_((HV)[reg][e]);                    \
          a[e] = fdot2_(wp0[(RB) + reg * 4 + e], hh, a[e]);        \
          b[e] = fdot2_(wp1[(RB) + reg * 4 + e], hh, b[e]);        \
        }                                                          \
      }
    HROUND_(ovr, 0)
    HROUND_(x1, 16)
    HROUND_(x2, 32)
    HROUND_(x3, 48)
    #undef HROUND_

    const float ga = (a[0] + a[1]) + (a[2] + a[3]);   // -log2e * (i|f)
    const float gb = (b[0] + b[1]) + (b[2] + b[3]);   // -2log2e*g | -log2e*o

    // activations on exp2-prescaled gates:
    // sg = sig(i|f) = rcp(1+exp2(ga)); qv = tanh(g) (role0) | sig(o) (role1).
    const float ea = ex2_(ga);
    const float sg = rcpf_(1.0f + ea);
    const float gbc = fminf(fmaxf(gb, -34.6f), 34.6f);
    const float eb = ex2_(gbc);
    const float qv = fmaf(qk2, eb, 1.0f) * rcpf_(1.0f + eb);
    const float ex = dppswap1_(sg * qv);      // role1 receives p = sig(i)*tanh(g)
    c = fmaf(sg, c, ex);                      // role1: sig(f)*c + p (role0 benign)
    const float hn = qv * tanhf_(c);          // role1: sig(o)*tanh(c)
    if (role) {
      hsf[par ^ 1][unit] = (_Float16)hn;
      hbp[unit] = (_Float16)hn;               // async store, never drained
    }
    hbp += hstep;
    if (tt + 3 < T_) xoff += xstep;           // wave-uniform clamp-advance
    barrier_lds_();
  };

  for (int tb = 0; tb < T_; tb += 2) {
    step(tb,     0, xwA);
    step(tb + 1, 1, xwB);
  }
}

// ---------------------------------------------------------------------------
// Emissions via MFMA (unchanged).
// ---------------------------------------------------------------------------
__global__ __launch_bounds__(256, 1)
void emis_kernel(const _Float16* __restrict__ hcat,
                 const float* __restrict__ Wp, const float* __restrict__ bp,
                 float* __restrict__ em)
{
  const int tid  = threadIdx.x;
  const int w    = tid >> 6;
  const int lane = tid & 63;
  const int lm   = lane & 15;
  const int quad = lane >> 4;

  f16x8 Bf[3][8];
  float bias[3];
  #pragma unroll
  for (int nt = 0; nt < 3; ++nt) {
    const int n = nt * 16 + lm;
    const bool valid = n < K_;
    bias[nt] = valid ? bp[n] : 0.0f;
    #pragma unroll
    for (int kt = 0; kt < 8; ++kt) {
      const int kb = kt * 32 + quad * 8;
      #pragma unroll
      for (int j = 0; j < 8; ++j)
        Bf[nt][kt][j] = valid ? (_Float16)Wp[(size_t)n * 256 + kb + j] : (_Float16)0.0f;
    }
  }

  #pragma unroll
  for (int q = 0; q < 4; ++q) {
    const int mt  = blockIdx.x * 16 + w * 4 + q;
    const int bt0 = mt * 16;

    f16x8 Af[8];
    const _Float16* ab = hcat + ((size_t)bt0 + lm) * 256;
    #pragma unroll
    for (int kt = 0; kt < 8; ++kt)
      Af[kt] = *(const f16x8*)(ab + kt * 32 + quad * 8);

    f32x4 acc[3];
    #pragma unroll
    for (int nt = 0; nt < 3; ++nt) acc[nt] = (f32x4){0.f, 0.f, 0.f, 0.f};
    #pragma unroll
    for (int kt = 0; kt < 8; ++kt)
      #pragma unroll
      for (int nt = 0; nt < 3; ++nt)
        acc[nt] = __builtin_amdgcn_mfma_f32_16x16x32_f16(Af[kt], Bf[nt][kt], acc[nt], 0, 0, 0);

    #pragma unroll
    for (int nt = 0; nt < 3; ++nt) {
      const int n = nt * 16 + lm;
      if (n < K_) {
        #pragma unroll
        for (int rg = 0; rg < 4; ++rg) {
          const int row = bt0 + quad * 4 + rg;
          em[(size_t)row * K_ + n] = acc[nt][rg] + bias[nt];
        }
      }
    }
  }
}

// ---------------------------------------------------------------------------
// Fused CRF denominator + numerator — REVERTED to the R1 readlane version
// (the R4 LDS round-trip regressed ~38 us: serial 1-wave loop exposes LDS
// latency per step; readlane hazards are cheaper).
// ---------------------------------------------------------------------------
__global__ __launch_bounds__(256)
void crf_dn_kernel(const float* __restrict__ em,
                   const int* __restrict__ labels, const int* __restrict__ lengths,
                   const float* __restrict__ start_t, const float* __restrict__ end_t,
                   const float* __restrict__ trans,
                   float* __restrict__ dn)
{
  const int b    = blockIdx.x;
  const int tid  = threadIdx.x;
  const int wv   = tid >> 6;
  const int lane = tid & 63;
  const int len  = lengths[b];
  const float* emb = em + (size_t)b * T_ * K_;

  __shared__ float s_num[3];
  __shared__ float s_den;

  if (wv == 0) {
    // ---------------- serial denominator, 1 wave ----------------
    float et[K_];
    #pragma unroll
    for (int j = 0; j < K_; ++j)
      et[j] = (lane < K_) ? __expf(trans[j * K_ + lane]) : 0.0f;

    float a0 = (lane < K_) ? (start_t[lane] + emb[lane]) : -1e30f;
    float m = a0;
    #pragma unroll
    for (int off = 32; off > 0; off >>= 1) m = fmaxf(m, __shfl_xor(m, off));
    float v = __expf(a0 - m);           // lanes >= 39 -> 0
    float off_acc = m;

    auto ldc = [&](int t) -> float {
      const int tc = (t < len) ? t : (len - 1);
      return (lane < K_) ? emb[(size_t)tc * K_ + lane] : 0.0f;
    };

    // 8 NAMED pipeline registers — no rotation moves.
    float eA = ldc(1), eB = ldc(2), eC = ldc(3), eD = ldc(4);
    float eE = ldc(5), eF = ldc(6), eG = ldc(7), eH = ldc(8);

    auto stepden = [&](float& ereg, int tt) {
      const float emc = ereg;
      ereg = ldc(tt + 8);               // reload same named reg for tt+8
      if (tt < len) {                   // wave-uniform guard
        const float pv = v;
        float s0 = 0.f, s1 = 0.f, s2 = 0.f, s3 = 0.f;
        #pragma unroll
        for (int j = 0; j < 36; j += 4) {
          s0 = fmaf(laneb_(pv, j),     et[j],     s0);
          s1 = fmaf(laneb_(pv, j + 1), et[j + 1], s1);
          s2 = fmaf(laneb_(pv, j + 2), et[j + 2], s2);
          s3 = fmaf(laneb_(pv, j + 3), et[j + 3], s3);
        }
        s0 = fmaf(laneb_(pv, 36), et[36], s0);
        s1 = fmaf(laneb_(pv, 37), et[37], s1);
        s2 = fmaf(laneb_(pv, 38), et[38], s2);
        v = ((s0 + s1) + (s2 + s3)) * __expf(emc);
        if ((tt & 1) == 0) {            // VALU-only renorm (all terms > 0)
          const float sc = laneb_(v, 0);
          v *= 1.0f / sc;
          off_acc += __logf(sc);
        }
      }
    };

    for (int t = 1; t < len; t += 8) {
      stepden(eA, t);     stepden(eB, t + 1);
      stepden(eC, t + 2); stepden(eD, t + 3);
      stepden(eE, t + 4); stepden(eF, t + 5);
      stepden(eG, t + 6); stepden(eH, t + 7);
    }

    float w = (lane < K_) ? v * __expf(end_t[lane]) : 0.0f;
    #pragma unroll
    for (int off = 32; off > 0; off >>= 1) w += __shfl_xor(w, off);
    if (lane == 0) s_den = off_acc + __logf(w);
  } else {
    // ---------------- parallel numerator, 3 waves ----------------
    const int idx = tid - 64;           // 0..191
    float acc = 0.0f;
    for (int t = 1 + idx; t < len; t += 192) {
      const int lp = labels[b * T_ + t - 1];
      const int lc = labels[b * T_ + t];
      acc += trans[lp * K_ + lc] + emb[(size_t)t * K_ + lc];
    }
    if (tid == 64) {                    // edge terms on one lane
      const int l0 = labels[b * T_];
      const int ll = labels[b * T_ + len - 1];
      acc += start_t[l0] + emb[l0] + end_t[ll];
    }
    #pragma unroll
    for (int off = 32; off > 0; off >>= 1) acc += __shfl_xor(acc, off);
    if (lane == 0) s_num[wv - 1] = acc;
  }
  __syncthreads();
  if (tid == 0) dn[b] = s_den - (s_num[0] + s_num[1] + s_num[2]);
}

// out = mean(dn) over the 64 batch elements (one wave).
__global__ void finalize_kernel(const float* __restrict__ dn, float* __restrict__ out)
{
  const int tid = threadIdx.x;   // 64
  float v = dn[tid];
  #pragma unroll
  for (int off = 32; off > 0; off >>= 1) v += __shfl_down(v, off);
  if (tid == 0) out[0] = v * (1.0f / 64.0f);
}

extern "C" void kernel_launch(void* const* d_in, const int* in_sizes, int n_in,
                              void* d_out, int out_size, void* d_ws, size_t ws_size,
                              hipStream_t stream)
{
  (void)in_sizes; (void)n_in; (void)out_size;
  const float* features = (const float*)d_in[0];
  const int*   lengths  = (const int*)d_in[1];
  const int*   labels   = (const int*)d_in[2];
  const float* Wih_f = (const float*)d_in[3];
  const float* Whh_f = (const float*)d_in[4];
  const float* bih_f = (const float*)d_in[5];
  const float* bhh_f = (const float*)d_in[6];
  const float* Wih_b = (const float*)d_in[7];
  const float* Whh_b = (const float*)d_in[8];
  const float* bih_b = (const float*)d_in[9];
  const float* bhh_b = (const float*)d_in[10];
  const float* Wp      = (const float*)d_in[11];
  const float* bp      = (const float*)d_in[12];
  const float* start_t = (const float*)d_in[13];
  const float* end_t   = (const float*)d_in[14];
  const float* trans   = (const float*)d_in[15];
  float* out = (float*)d_out;

  // ws layout (bytes): hcat f16 [0, 26214400) ; em f32 [26214400, +7987200) ;
  // dn 256 B ; xw f16 [34202112, +104857600) if ws is big enough.
  char* wsc = (char*)d_ws;
  _Float16* hcatH = (_Float16*)wsc;
  float*    em    = (float*)(wsc + 26214400);
  float*    dn    = (float*)(wsc + 26214400 + 7987200);
  _Float16* xwH   = (_Float16*)(wsc + 34202112);
  const bool big  = ws_size >= (size_t)34202112 + 104857600;

  if (big) {
    hipLaunchKernelGGL(xw_kernel, dim3(200), dim3(256), 0, stream,
                       features, Wih_f, Wih_b, xwH);
    hipLaunchKernelGGL((lstm_kernel<1>), dim3(2 * B_), dim3(256), 0, stream,
                       features, Wih_f, Whh_f, bih_f, bhh_f,
                       Wih_b, Whh_b, bih_b, bhh_b, xwH, hcatH);
  } else {
    hipLaunchKernelGGL((lstm_kernel<0>), dim3(2 * B_), dim3(256), 0, stream,
                       features, Wih_f, Whh_f, bih_f, bhh_f,
                       Wih_b, Whh_b, bih_b, bhh_b, xwH, hcatH);
  }
  hipLaunchKernelGGL(emis_kernel, dim3(BT_ / 256), dim3(256), 0, stream,
                     hcatH, Wp, bp, em);
  hipLaunchKernelGGL(crf_dn_kernel, dim3(B_), dim3(256), 0, stream,
                     em, labels, lengths, start_t, end_t, trans, dn);
  hipLaunchKernelGGL(finalize_kernel, dim3(1), dim3(64), 0, stream,
                     dn, out);
}